// Round 1
// 222.144 us; speedup vs baseline: 1.0837x; 1.0837x over previous
//
#include <hip/hip_runtime.h>
#include <stdint.h>

// N=16384 points, K=10 (fixed by setup_inputs).
#define NPTS   16384
#define TOPK   10
#define NBX    64
#define NBY    64
#define NBK    (NBX * NBY)        // 4096 cells over (x,y)
#define XMIN   (-5.0f)
#define INVBW  (6.4f)             // NBX / 10.0
#define SENT_STEP 0x4000u         // one ulp at masked-key granularity (= idx field size)

// ws layout (bytes):
//   0       accum[4] floats (sparsity, scale, opacity, smooth)
//   256     hist[NBK] uint          [256, 16640)
//   16640   cnt[NBK] uint           [16640, 33024)
//   33024   base[NBK+1] uint        [33024, 49412)
//   49664   r2m[NPTS] uint          (masked upper bound on 10-NN d2)
//   115200  sorted[NPTS] float4     (x,y,z,opacity) cell-ordered by (bx,by)
// memset zeroes [0, 33024).

__device__ __forceinline__ unsigned umin_(unsigned a, unsigned b) { return a < b ? a : b; }
__device__ __forceinline__ unsigned umax_(unsigned a, unsigned b) { return a > b ? a : b; }

// Branchless ascending insert (19 independent min/max).
__device__ __forceinline__ void chain_insert(unsigned a[TOPK], unsigned key) {
#pragma unroll
    for (int k = TOPK - 1; k > 0; --k) a[k] = umin_(umax_(a[k - 1], key), a[k]);
    a[0] = umin_(a[0], key);
}

__device__ __forceinline__ int cell_of(float v) {
    int b = (int)((v - XMIN) * INVBW);
    return min(max(b, 0), NBX - 1);
}

// ---- fused trivial losses + 2-D cell histogram ----------------------------
__global__ __launch_bounds__(256) void setup_kernel(
    const float* __restrict__ pos, const float* __restrict__ opac,
    const float* __restrict__ scales, float* __restrict__ accum,
    unsigned* __restrict__ hist)
{
    int i = blockIdx.x * 256 + threadIdx.x;
    float o = opac[i];
    float d = o - 0.5f;
    float s_sp = fabsf(o);
    float s_op = d * d;
    float s_sc = fabsf(scales[3 * i] - 1.0f) + fabsf(scales[3 * i + 1] - 1.0f)
               + fabsf(scales[3 * i + 2] - 1.0f);
    int bx = cell_of(pos[3 * i]);
    int by = cell_of(pos[3 * i + 1]);
    atomicAdd(&hist[bx * NBY + by], 1u);
#pragma unroll
    for (int off = 32; off > 0; off >>= 1) {
        s_sp += __shfl_down(s_sp, off, 64);
        s_sc += __shfl_down(s_sc, off, 64);
        s_op += __shfl_down(s_op, off, 64);
    }
    if ((threadIdx.x & 63) == 0) {
        atomicAdd(&accum[0], s_sp);
        atomicAdd(&accum[1], s_sc);
        atomicAdd(&accum[2], s_op);
    }
}

// exclusive scan over 4096 bins: 1024 threads, 4 bins each + Hillis-Steele.
__global__ __launch_bounds__(1024) void prefix_scan(
    const unsigned* __restrict__ hist, unsigned* __restrict__ base)
{
    __shared__ unsigned tmp[1024];
    const int t = threadIdx.x;
    uint4 h = ((const uint4*)hist)[t];
    unsigned s1 = h.x + h.y;
    unsigned s2 = s1 + h.z;
    unsigned s3 = s2 + h.w;
    tmp[t] = s3;
    __syncthreads();
    for (int off = 1; off < 1024; off <<= 1) {
        unsigned v = (t >= off) ? tmp[t - off] : 0u;
        __syncthreads();
        tmp[t] += v;
        __syncthreads();
    }
    unsigned incl = tmp[t];
    unsigned excl = incl - s3;
    base[4 * t + 0] = excl;
    base[4 * t + 1] = excl + h.x;
    base[4 * t + 2] = excl + s1;
    base[4 * t + 3] = excl + s2;
    if (t == 1023) base[NBK] = incl;
}

__global__ __launch_bounds__(256) void scatter_sorted(
    const float* __restrict__ pos, const float* __restrict__ opac,
    const unsigned* __restrict__ base, unsigned* __restrict__ cnt,
    float4* __restrict__ sorted)
{
    int i = blockIdx.x * 256 + threadIdx.x;
    float x = pos[3 * i], y = pos[3 * i + 1], z = pos[3 * i + 2];
    int b = cell_of(x) * NBY + cell_of(y);
    unsigned p = base[b] + atomicAdd(&cnt[b], 1u);
    sorted[p] = make_float4(x, y, z, opac[i]);
}

// ---- pass 1: per-point upper bound on 10-NN d2 ----------------------------
// 8 threads/point, each a CONTIGUOUS 64-candidate segment of the +/-256
// window in cell-sorted order (same-column, y-near points -> tight bound).
__global__ __launch_bounds__(256) void knn_pass1(
    const float4* __restrict__ sorted, unsigned* __restrict__ r2m)
{
    const int t8  = blockIdx.x * 256 + threadIdx.x;
    const int s   = t8 >> 3;
    const int sub = t8 & 7;
    const int dir = sub >> 2;                  // 0 right, 1 left
    const int start = 1 + (sub & 3) * 64;
    const float4 me = sorted[s];

    unsigned a[TOPK];
#pragma unroll
    for (int k = 0; k < TOPK; ++k) a[k] = 0xFFFFFFFFu;

#pragma unroll 4
    for (int t = 0; t < 64; ++t) {
        int p = dir ? (s - start - t) : (s + start + t);
        int pc = min(max(p, 0), NPTS - 1);
        float4 c = sorted[pc];
        float dx = c.x - me.x, dy = c.y - me.y, dz = c.z - me.z;
        float d2 = fmaf(dx, dx, fmaf(dy, dy, dz * dz));
        unsigned key = (__float_as_uint(d2) & 0xFFFFC000u) | (unsigned)pc;
        if (p < 0 || p >= NPTS) key = 0xFFFFFFFFu;
        chain_insert(a, key);
    }
    // merge the 8 segment lists (all 8 lanes converge to the same top-10)
#pragma unroll
    for (int w = 1; w <= 4; w <<= 1) {
        unsigned tmp[TOPK];
#pragma unroll
        for (int k = 0; k < TOPK; ++k) tmp[k] = (unsigned)__shfl_xor((int)a[k], w, 64);
#pragma unroll
        for (int k = 0; k < TOPK; ++k) chain_insert(a, tmp[k]);
    }
    if (sub == 0) r2m[s] = a[TOPK - 1] & 0xFFFFC000u;
}

// ---- pass 2: exact 10-NN over the (x,y)-window cell runs + smoothness -----
// 16 lanes/point (4 points/wave). For each x-column in [me.x +/- R], scan the
// contiguous y-run [me.y +/- R] (cell order makes it one [lo,hi) interval).
// Accumulator seeded with the R2 sentinel so the insert gate doubles as the
// radius filter. Wave->point mapping permuted for cross-block load balance.
__global__ __launch_bounds__(256) void knn_pass2(
    const float4* __restrict__ sorted, const unsigned* __restrict__ r2m,
    const unsigned* __restrict__ base, float* __restrict__ accum)
{
    __shared__ float ssum;
    if (threadIdx.x == 0) ssum = 0.0f;
    __syncthreads();

    const int wv  = threadIdx.x >> 6;           // wave in block
    const int gw  = (threadIdx.x >> 4) & 3;     // group in wave
    const int sub = threadIdx.x & 15;
    const int W   = blockIdx.x * 4 + wv;        // global wave id in [0,4096)
    const int Q   = (W * 1531) & 4095;          // balance permutation (odd mult)
    const int s   = Q * 4 + gw;                 // groups in a wave stay adjacent

    const float4 me = sorted[s];
    const unsigned sentinel = r2m[s] + SENT_STEP;   // > true 10-NN masked d2
    const float R = sqrtf(__uint_as_float(sentinel)) + 1e-6f;

    int bxlo = (int)((me.x - R - XMIN) * INVBW); bxlo = min(max(bxlo, 0), NBX - 1);
    int bxhi = (int)((me.x + R - XMIN) * INVBW); bxhi = min(max(bxhi, 0), NBX - 1);
    int bylo = (int)((me.y - R - XMIN) * INVBW); bylo = min(max(bylo, 0), NBY - 1);
    int byhi = (int)((me.y + R - XMIN) * INVBW); byhi = min(max(byhi, 0), NBY - 1);

    unsigned a[TOPK];
#pragma unroll
    for (int k = 0; k < TOPK; ++k) a[k] = sentinel;

    for (int bx = bxlo; bx <= bxhi; ++bx) {
        const int lo = (int)base[bx * NBY + bylo];
        const int hi = (int)base[bx * NBY + byhi + 1];
        const int niter = (hi - lo + 31) >> 5;      // uniform within group
        int p = lo + sub;
        for (int it = 0; it < niter; ++it) {
            int p1 = p + 16;
            int pc0 = min(p,  NPTS - 1);
            int pc1 = min(p1, NPTS - 1);
            float4 c0 = sorted[pc0];
            float4 c1 = sorted[pc1];
            float dx0 = c0.x - me.x, dy0 = c0.y - me.y, dz0 = c0.z - me.z;
            float dx1 = c1.x - me.x, dy1 = c1.y - me.y, dz1 = c1.z - me.z;
            float d20 = fmaf(dx0, dx0, fmaf(dy0, dy0, dz0 * dz0));
            float d21 = fmaf(dx1, dx1, fmaf(dy1, dy1, dz1 * dz1));
            unsigned k0 = (__float_as_uint(d20) & 0xFFFFC000u) | (unsigned)pc0;
            unsigned k1 = (__float_as_uint(d21) & 0xFFFFC000u) | (unsigned)pc1;
            if (p  >= hi || pc0 == s) k0 = 0xFFFFFFFFu;
            if (p1 >= hi || pc1 == s) k1 = 0xFFFFFFFFu;
            unsigned kmin = umin_(k0, k1), kmax = umax_(k0, k1);
            if (kmin < a[TOPK - 1]) {
                chain_insert(a, kmin);
                if (kmax < a[TOPK - 1]) chain_insert(a, kmax);
            }
            p += 32;
        }
    }

    // butterfly merge within the 16-lane group -> all lanes share the top-10
#pragma unroll
    for (int w = 8; w >= 1; w >>= 1) {
        unsigned tmp[TOPK];
#pragma unroll
        for (int k = 0; k < TOPK; ++k) tmp[k] = (unsigned)__shfl_xor((int)a[k], w, 64);
#pragma unroll
        for (int k = 0; k < TOPK; ++k) chain_insert(a, tmp[k]);
    }

    float v = 0.0f;
    if (sub < TOPK) {
        int j = (int)(a[sub] & 0x3FFFu);
        v = fabsf(me.w - sorted[j].w);
    }
    v += __shfl_down(v, 8, 64);
    v += __shfl_down(v, 4, 64);
    v += __shfl_down(v, 2, 64);
    v += __shfl_down(v, 1, 64);
    if (sub == 0) atomicAdd(&ssum, v);
    __syncthreads();
    if (threadIdx.x == 0) atomicAdd(&accum[3], ssum);
}

// ---- combine --------------------------------------------------------------
__global__ void combine(const float* __restrict__ accum, float* __restrict__ out) {
    if (threadIdx.x == 0) {
        const float n = (float)NPTS;
        float sparsity = accum[0] / n;
        float scale    = accum[1] / (3.0f * n);
        float opacl    = accum[2] / n;
        float smooth   = accum[3] / (n * 10.0f);
        out[0] = 0.01f * sparsity + 0.1f * smooth + scale + opacl;
    }
}

extern "C" void kernel_launch(void* const* d_in, const int* in_sizes, int n_in,
                              void* d_out, int out_size, void* d_ws, size_t ws_size,
                              hipStream_t stream)
{
    const float* pos    = (const float*)d_in[0];
    const float* opac   = (const float*)d_in[1];
    const float* scales = (const float*)d_in[2];
    float* out = (float*)d_out;

    char* ws = (char*)d_ws;
    float*    accum  = (float*)ws;
    unsigned* hist   = (unsigned*)(ws + 256);
    unsigned* cnt    = (unsigned*)(ws + 16640);
    unsigned* base   = (unsigned*)(ws + 33024);
    unsigned* r2m    = (unsigned*)(ws + 49664);
    float4*   sorted = (float4*)(ws + 115200);

    hipMemsetAsync(ws, 0, 33024, stream);

    setup_kernel  <<<NPTS / 256, 256, 0, stream>>>(pos, opac, scales, accum, hist);
    prefix_scan   <<<1, 1024, 0, stream>>>(hist, base);
    scatter_sorted<<<NPTS / 256, 256, 0, stream>>>(pos, opac, base, cnt, sorted);
    knn_pass1     <<<NPTS * 8 / 256, 256, 0, stream>>>(sorted, r2m);
    knn_pass2     <<<NPTS / 16, 256, 0, stream>>>(sorted, r2m, base, accum);
    combine       <<<1, 64, 0, stream>>>(accum, out);
}

// Round 2
// 202.578 us; speedup vs baseline: 1.1884x; 1.0966x over previous
//
#include <hip/hip_runtime.h>
#include <stdint.h>

// N=16384 points, K=10 (fixed by setup_inputs).
#define NPTS   16384
#define TOPK   10
#define NBX    32                 // 32x32x32 cells over [-5,5]^3
#define NBK    (32 * 32 * 32)
#define XMIN   (-5.0f)
#define INVBW  (3.2f)             // 32 / 10.0
#define SENT_STEP 0x4000u         // one ulp at masked-key granularity (= idx field)

// ws layout (bytes):
//   0       accum[4] floats (sparsity, scale, opacity, smooth)
//   256     hist[NBK] uint  -> re-zeroed by prefix_scan, reused as cnt
//   131328  base[NBK+1] uint
//   262464  r2m[NPTS] uint        (masked upper bound on 10-NN d2)
//   328064  sorted[NPTS] float4   (x,y,z,opacity) ordered by (bx,by,bz)
// total ~590 KB. memset zeroes [0, 131328).

__device__ __forceinline__ unsigned umin_(unsigned a, unsigned b) { return a < b ? a : b; }
__device__ __forceinline__ unsigned umax_(unsigned a, unsigned b) { return a > b ? a : b; }

// Branchless ascending insert (19 independent min/max).
__device__ __forceinline__ void chain_insert(unsigned a[TOPK], unsigned key) {
#pragma unroll
    for (int k = TOPK - 1; k > 0; --k) a[k] = umin_(umax_(a[k - 1], key), a[k]);
    a[0] = umin_(a[0], key);
}

__device__ __forceinline__ void ce_(unsigned &x, unsigned &y) {
    unsigned lo = umin_(x, y); y = umax_(x, y); x = lo;
}

// Merge two sorted 10-lists (ours + partner lane's) into our sorted top-10.
// Bitonic halver (10 mins) + bitonic merge network for a length-10 bitonic
// sequence (15 CEs; virtual +INF pads at 10..15 never interact).
__device__ __forceinline__ void merge_shfl(unsigned a[TOPK], int w) {
    unsigned b[TOPK];
#pragma unroll
    for (int k = 0; k < TOPK; ++k) b[k] = (unsigned)__shfl_xor((int)a[k], w, 64);
#pragma unroll
    for (int k = 0; k < TOPK; ++k) a[k] = umin_(a[k], b[TOPK - 1 - k]);
    ce_(a[0], a[8]); ce_(a[1], a[9]);
    ce_(a[0], a[4]); ce_(a[1], a[5]); ce_(a[2], a[6]); ce_(a[3], a[7]);
    ce_(a[0], a[2]); ce_(a[1], a[3]); ce_(a[4], a[6]); ce_(a[5], a[7]);
    ce_(a[0], a[1]); ce_(a[2], a[3]); ce_(a[4], a[5]); ce_(a[6], a[7]); ce_(a[8], a[9]);
}

__device__ __forceinline__ int cellf(float v) {
    int b = (int)((v - XMIN) * INVBW);
    return min(max(b, 0), NBX - 1);
}

// ---- fused trivial losses + 3-D cell histogram ----------------------------
__global__ __launch_bounds__(256) void setup_kernel(
    const float* __restrict__ pos, const float* __restrict__ opac,
    const float* __restrict__ scales, float* __restrict__ accum,
    unsigned* __restrict__ hist)
{
    int i = blockIdx.x * 256 + threadIdx.x;
    float o = opac[i];
    float d = o - 0.5f;
    float s_sp = fabsf(o);
    float s_op = d * d;
    float s_sc = fabsf(scales[3 * i] - 1.0f) + fabsf(scales[3 * i + 1] - 1.0f)
               + fabsf(scales[3 * i + 2] - 1.0f);
    int bx = cellf(pos[3 * i]);
    int by = cellf(pos[3 * i + 1]);
    int bz = cellf(pos[3 * i + 2]);
    atomicAdd(&hist[(bx << 10) | (by << 5) | bz], 1u);
#pragma unroll
    for (int off = 32; off > 0; off >>= 1) {
        s_sp += __shfl_down(s_sp, off, 64);
        s_sc += __shfl_down(s_sc, off, 64);
        s_op += __shfl_down(s_op, off, 64);
    }
    if ((threadIdx.x & 63) == 0) {
        atomicAdd(&accum[0], s_sp);
        atomicAdd(&accum[1], s_sc);
        atomicAdd(&accum[2], s_op);
    }
}

// Exclusive scan over 32768 bins: 1024 threads x 32 bins + Hillis-Steele.
// Also re-zeroes hist in place (it becomes the scatter cnt array).
__global__ __launch_bounds__(1024) void prefix_scan(
    unsigned* __restrict__ hist, unsigned* __restrict__ base)
{
    __shared__ unsigned tmp[1024];
    const int t = threadIdx.x;
    unsigned loc[32];
    uint4* h4 = (uint4*)(hist + t * 32);
#pragma unroll
    for (int j = 0; j < 8; ++j) {
        uint4 h = h4[j];
        loc[4 * j + 0] = h.x; loc[4 * j + 1] = h.y;
        loc[4 * j + 2] = h.z; loc[4 * j + 3] = h.w;
    }
    unsigned run = 0;
#pragma unroll
    for (int j = 0; j < 32; ++j) { unsigned v = loc[j]; loc[j] = run; run += v; }
    tmp[t] = run;
    __syncthreads();
    for (int off = 1; off < 1024; off <<= 1) {
        unsigned v = (t >= off) ? tmp[t - off] : 0u;
        __syncthreads();
        tmp[t] += v;
        __syncthreads();
    }
    const unsigned excl = tmp[t] - run;
    uint4* b4 = (uint4*)(base + t * 32);
#pragma unroll
    for (int j = 0; j < 8; ++j) {
        b4[j] = make_uint4(loc[4 * j] + excl, loc[4 * j + 1] + excl,
                           loc[4 * j + 2] + excl, loc[4 * j + 3] + excl);
        h4[j] = make_uint4(0u, 0u, 0u, 0u);
    }
    if (t == 1023) base[NBK] = NPTS;
}

__global__ __launch_bounds__(256) void scatter_sorted(
    const float* __restrict__ pos, const float* __restrict__ opac,
    const unsigned* __restrict__ base, unsigned* __restrict__ cnt,
    float4* __restrict__ sorted)
{
    int i = blockIdx.x * 256 + threadIdx.x;
    float x = pos[3 * i], y = pos[3 * i + 1], z = pos[3 * i + 2];
    int b = (cellf(x) << 10) | (cellf(y) << 5) | cellf(z);
    unsigned p = base[b] + atomicAdd(&cnt[b], 1u);
    sorted[p] = make_float4(x, y, z, opac[i]);
}

// ---- pass 1: per-point upper bound on 10-NN d2 ----------------------------
// 8 threads/point, each a CONTIGUOUS 32-candidate segment of the +/-128
// window in 3-D cell order (local in x, y AND z -> tight bound everywhere).
__global__ __launch_bounds__(256) void knn_pass1(
    const float4* __restrict__ sorted, unsigned* __restrict__ r2m)
{
    const int t8  = blockIdx.x * 256 + threadIdx.x;
    const int s   = t8 >> 3;
    const int sub = t8 & 7;
    const int dir = sub >> 2;                  // 0 right, 1 left
    const int start = 1 + (sub & 3) * 32;
    const float4 me = sorted[s];

    unsigned a[TOPK];
#pragma unroll
    for (int k = 0; k < TOPK; ++k) a[k] = 0xFFFFFFFFu;

#pragma unroll 4
    for (int t = 0; t < 32; ++t) {
        int p = dir ? (s - start - t) : (s + start + t);
        int pc = min(max(p, 0), NPTS - 1);
        float4 c = sorted[pc];
        float dx = c.x - me.x, dy = c.y - me.y, dz = c.z - me.z;
        float d2 = fmaf(dx, dx, fmaf(dy, dy, dz * dz));
        unsigned key = (__float_as_uint(d2) & 0xFFFFC000u) | (unsigned)pc;
        if (p < 0 || p >= NPTS) key = 0xFFFFFFFFu;
        chain_insert(a, key);
    }
    merge_shfl(a, 1);
    merge_shfl(a, 2);
    merge_shfl(a, 4);
    if (sub == 0) r2m[s] = a[TOPK - 1] & 0xFFFFC000u;
}

// ---- pass 2: exact 10-NN over the 3-D cell window + smoothness ------------
// 16 lanes/point (4 points/wave). For each (bx,by) column pair in the window,
// scan the contiguous z-run [me.z +/- R] (one base[] interval per pair).
// Next pair's bounds are prefetched under the current pair's scan.
// Accumulator seeded with the R2 sentinel so the insert gate doubles as the
// radius filter. Wave->point mapping permuted for cross-block load balance.
__global__ __launch_bounds__(256) void knn_pass2(
    const float4* __restrict__ sorted, const unsigned* __restrict__ r2m,
    const unsigned* __restrict__ base, float* __restrict__ accum)
{
    __shared__ float ssum;
    if (threadIdx.x == 0) ssum = 0.0f;
    __syncthreads();

    const int wv  = threadIdx.x >> 6;           // wave in block
    const int gw  = (threadIdx.x >> 4) & 3;     // group in wave
    const int sub = threadIdx.x & 15;
    const int W   = blockIdx.x * 4 + wv;        // global wave id in [0,4096)
    const int Q   = (W * 1531) & 4095;          // balance permutation (odd mult)
    const int s   = Q * 4 + gw;                 // groups in a wave stay adjacent

    const float4 me = sorted[s];
    const unsigned sentinel = r2m[s] + SENT_STEP;   // > true 10-NN masked key
    const float R = sqrtf(__uint_as_float(sentinel)) + 1e-6f;

    const int bxlo = cellf(me.x - R), bxhi = cellf(me.x + R);
    const int bylo = cellf(me.y - R), byhi = cellf(me.y + R);
    const int bzlo = cellf(me.z - R), bzhi = cellf(me.z + R);

    unsigned a[TOPK];
#pragma unroll
    for (int k = 0; k < TOPK; ++k) a[k] = sentinel;

    int bx = bxlo, by = bylo;
    {
        const int cb = (bx << 10) | (by << 5);
        int lo = (int)base[cb + bzlo];
        int hi = (int)base[cb + bzhi + 1];
        for (;;) {
            int nbx = bx, nby = by + 1;
            if (nby > byhi) { nby = bylo; nbx = bx + 1; }
            const bool more = (nbx <= bxhi);
            int nlo = 0, nhi = 0;
            if (more) {                          // prefetch next pair's bounds
                const int ncb = (nbx << 10) | (nby << 5);
                nlo = (int)base[ncb + bzlo];
                nhi = (int)base[ncb + bzhi + 1];
            }
            const int niter = (hi - lo + 31) >> 5;
            int p = lo + sub;
            for (int it = 0; it < niter; ++it) {
                int p1 = p + 16;
                int pc0 = min(p,  NPTS - 1);
                int pc1 = min(p1, NPTS - 1);
                float4 c0 = sorted[pc0];
                float4 c1 = sorted[pc1];
                float dx0 = c0.x - me.x, dy0 = c0.y - me.y, dz0 = c0.z - me.z;
                float dx1 = c1.x - me.x, dy1 = c1.y - me.y, dz1 = c1.z - me.z;
                float d20 = fmaf(dx0, dx0, fmaf(dy0, dy0, dz0 * dz0));
                float d21 = fmaf(dx1, dx1, fmaf(dy1, dy1, dz1 * dz1));
                unsigned k0 = (__float_as_uint(d20) & 0xFFFFC000u) | (unsigned)pc0;
                unsigned k1 = (__float_as_uint(d21) & 0xFFFFC000u) | (unsigned)pc1;
                if (p  >= hi || pc0 == s) k0 = 0xFFFFFFFFu;
                if (p1 >= hi || pc1 == s) k1 = 0xFFFFFFFFu;
                unsigned kmin = umin_(k0, k1), kmax = umax_(k0, k1);
                if (kmin < a[TOPK - 1]) {
                    chain_insert(a, kmin);
                    if (kmax < a[TOPK - 1]) chain_insert(a, kmax);
                }
                p += 32;
            }
            if (!more) break;
            lo = nlo; hi = nhi; bx = nbx; by = nby;
        }
    }

    // merge within the 16-lane group -> all lanes share the top-10
    merge_shfl(a, 1);
    merge_shfl(a, 2);
    merge_shfl(a, 4);
    merge_shfl(a, 8);

    float v = 0.0f;
    if (sub < TOPK) {
        int j = (int)(a[sub] & 0x3FFFu);
        v = fabsf(me.w - sorted[j].w);
    }
    v += __shfl_down(v, 8, 64);
    v += __shfl_down(v, 4, 64);
    v += __shfl_down(v, 2, 64);
    v += __shfl_down(v, 1, 64);
    if (sub == 0) atomicAdd(&ssum, v);
    __syncthreads();
    if (threadIdx.x == 0) atomicAdd(&accum[3], ssum);
}

// ---- combine --------------------------------------------------------------
__global__ void combine(const float* __restrict__ accum, float* __restrict__ out) {
    if (threadIdx.x == 0) {
        const float n = (float)NPTS;
        float sparsity = accum[0] / n;
        float scale    = accum[1] / (3.0f * n);
        float opacl    = accum[2] / n;
        float smooth   = accum[3] / (n * 10.0f);
        out[0] = 0.01f * sparsity + 0.1f * smooth + scale + opacl;
    }
}

extern "C" void kernel_launch(void* const* d_in, const int* in_sizes, int n_in,
                              void* d_out, int out_size, void* d_ws, size_t ws_size,
                              hipStream_t stream)
{
    const float* pos    = (const float*)d_in[0];
    const float* opac   = (const float*)d_in[1];
    const float* scales = (const float*)d_in[2];
    float* out = (float*)d_out;

    char* ws = (char*)d_ws;
    float*    accum  = (float*)ws;
    unsigned* histcnt= (unsigned*)(ws + 256);      // hist, then cnt after scan
    unsigned* base   = (unsigned*)(ws + 131328);
    unsigned* r2m    = (unsigned*)(ws + 262464);
    float4*   sorted = (float4*)(ws + 328064);

    hipMemsetAsync(ws, 0, 131328, stream);

    setup_kernel  <<<NPTS / 256, 256, 0, stream>>>(pos, opac, scales, accum, histcnt);
    prefix_scan   <<<1, 1024, 0, stream>>>(histcnt, base);
    scatter_sorted<<<NPTS / 256, 256, 0, stream>>>(pos, opac, base, histcnt, sorted);
    knn_pass1     <<<NPTS * 8 / 256, 256, 0, stream>>>(sorted, r2m);
    knn_pass2     <<<NPTS / 16, 256, 0, stream>>>(sorted, r2m, base, accum);
    combine       <<<1, 64, 0, stream>>>(accum, out);
}